// Round 3
// baseline (320.308 us; speedup 1.0000x reference)
//
#include <hip/hip_runtime.h>

// RRSVM rank-weighted pooling, 3x3 / stride 2 / pad 1.
// x: [B=32, C=64, H=112, W=112] fp32;  s: [C, 3, 3] fp32
// out0: [B,C,56,56] fp32 ; out1: order [B,C,56,56,9] written as fp32.
//
// R8: barrier-free direct-gather. R7 showed sort VALU is fully hidden
// (CE slimming = 0 delta) and the deferred store = 0 delta; remaining
// exposure is the block-wide vmcnt(0)+barrier sleep after LDS staging.
// So: drop input staging entirely -- each thread gathers its 9 window
// values directly from global (stride-2 dup reads are L1 hits; HBM
// fetch unchanged), sorts in registers, and the only LDS is the
// per-WAVE-disjoint order-transpose buffer. Cross-lane visibility
// within a wave needs only s_waitcnt lgkmcnt(0) -- NO __syncthreads in
// the kernel. Waves are fully independent; all stores nontemporal and
// issued at wave end (s_endpgm never waits on them).

typedef float nfloat4 __attribute__((ext_vector_type(4)));

constexpr int B  = 32;
constexpr int C  = 64;
constexpr int H  = 112;
constexpr int W  = 112;
constexpr int HO = 56;
constexpr int WO = 56;
constexpr int KK = 9;
constexpr int NPIX = HO * WO;          // 3136 windows per (b,c) plane
constexpr int BLK  = 256;
constexpr int RPT  = 4;                // window-rows per block (1 per wave)

__global__ __launch_bounds__(BLK, 8) void rrsvm_kernel(
    const float* __restrict__ x, const float* __restrict__ s,
    float* __restrict__ out, float* __restrict__ order)
{
    // Per-wave-disjoint order staging: wave w owns floats [w*504, w*504+504).
    __shared__ float lorder[RPT * WO * KK];    // 8064 B

    const int plane = blockIdx.y;              // b*C + c (block-uniform)
    const int ho0   = blockIdx.x;              // tile of 4 window-rows
    const int tid   = threadIdx.x;
    const int w     = tid >> 6;                // wave id 0..3 -> window-row
    const int lane  = tid & 63;                // lane -> window-col (56 live)
    const int c     = plane & (C - 1);

    const bool live = (lane < WO);
    const int  lc   = live ? lane : 0;
    const int  ho   = ho0 * RPT + w;           // 0..55

    const float* xp = x + (size_t)plane * (H * W);

    // ---- Direct gather: rows 2*ho-1..2*ho+1, cols 2*lc-1..2*lc+1.
    // Only row -1 (ho==0,dy==0) and col -1 (lc==0,dx==0) are pad-zero;
    // clamp the address (stays in-bounds) and mask the value.
    float v[KK];
    float fid[KK];
#pragma unroll
    for (int dy = 0; dy < 3; ++dy) {
        const int r  = 2 * ho - 1 + dy;        // -1..111
        const int rr = r < 0 ? 0 : r;
        const float* rp = xp + rr * W;
#pragma unroll
        for (int dx = 0; dx < 3; ++dx) {
            const int k  = dy * 3 + dx;
            const int cl = 2 * lc - 1 + dx;    // -1..111
            const int cc = cl < 0 ? 0 : cl;
            const float val = rp[cc];
            v[k]   = (r >= 0 && cl >= 0) ? val : 0.0f;
            fid[k] = (float)k;                 // compile-time constant
        }
    }

    // ---- Sort descending by value; exact tie -> smaller index first.
    // (ids as floats: comparison exact for 0..8.)  Value path via
    // fmax/fmin (no NaNs in input); id path needs the full predicate.
    auto CE = [&](int a, int b) {
        const float va = v[a],   vb = v[b];
        const float fa = fid[a], fb = fid[b];
        const bool sw = (va < vb) || ((va == vb) && (fa > fb));
        v[a]   = fmaxf(va, vb);
        v[b]   = fminf(va, vb);
        fid[a] = sw ? fb : fa;
        fid[b] = sw ? fa : fb;
    };
    // Batcher odd-even mergesort on 0..7 (19 CEs) + insertion of 8 (8 CEs).
    CE(0,1); CE(2,3); CE(4,5); CE(6,7);
    CE(0,2); CE(1,3); CE(4,6); CE(5,7);
    CE(1,2); CE(5,6);
    CE(0,4); CE(1,5); CE(2,6); CE(3,7);
    CE(2,4); CE(3,5);
    CE(1,2); CE(3,4); CE(5,6);
    CE(7,8); CE(6,7); CE(5,6); CE(4,5); CE(3,4); CE(2,3); CE(1,2); CE(0,1);

    // ---- Weighted sum with per-channel rank weights (block-uniform c).
    const float* sc = s + c * KK;
    float acc = 0.0f;
#pragma unroll
    for (int k = 0; k < KK; ++k) acc = fmaf(v[k], sc[k], acc);

    // ---- Stage this wave's order chunk into its own LDS region.
    if (live) {
        const int widx = w * WO + lane;        // window within tile, 0..223
#pragma unroll
        for (int k = 0; k < KK; ++k)
            lorder[widx * KK + k] = fid[k];    // stride 9 -> 2-way, free
    }

    // In-wave cross-lane visibility: all prior ds_writes complete before
    // any following ds_read issues. No __syncthreads needed (region is
    // wave-disjoint); "memory" clobber pins the LDS ops on either side.
    asm volatile("s_waitcnt lgkmcnt(0)" ::: "memory");

    // ---- Per-wave coalesced nontemporal float4 writeback (126 float4).
    const nfloat4* __restrict__ lb = (const nfloat4*)&lorder[w * WO * KK];
    nfloat4* __restrict__ ob =
        (nfloat4*)(order + ((size_t)plane * NPIX + (size_t)ho * WO) * KK);
#pragma unroll
    for (int i = lane; i < WO * KK / 4; i += 64)   // iter 1: all; iter 2: lane<62
        __builtin_nontemporal_store(lb[i], ob + i);

    if (live)
        __builtin_nontemporal_store(acc, out + (size_t)plane * NPIX + ho * WO + lane);
}

extern "C" void kernel_launch(void* const* d_in, const int* in_sizes, int n_in,
                              void* d_out, int out_size, void* d_ws, size_t ws_size,
                              hipStream_t stream) {
    const float* x = (const float*)d_in[0];
    const float* s = (const float*)d_in[1];
    float* out   = (float*)d_out;
    float* order = out + (size_t)B * C * NPIX;   // second output, flat after first

    dim3 grid(HO / RPT, B * C);                  // (14, 2048)
    rrsvm_kernel<<<grid, dim3(BLK), 0, stream>>>(x, s, out, order);
}

// Round 4
// 313.908 us; speedup vs baseline: 1.0204x; 1.0204x over previous
//
#include <hip/hip_runtime.h>

// RRSVM rank-weighted pooling, 3x3 / stride 2 / pad 1.
// x: [B=32, C=64, H=112, W=112] fp32;  s: [C, 3, 3] fp32
// out0: [B,C,56,56] fp32 ; out1: order [B,C,56,56,9] written as fp32.
//
// R9 = R7 (best, 313.25us) + sector-aligned out writeback.
// R8 post-mortem: direct gather regressed (+7us) -> staged reads + the
// two-barrier structure are NOT the bottleneck. Remaining write-path
// flaw: per-wave out rows are 224B chunks, never 64B-sector-aligned;
// NT stores evict L2 lines early so sectors shared between rows written
// by different waves/blocks become HBM read-modify-writes (~15MB hidden
// fetch on the 25.7MB out stream). Fix: stage the block's 224-float out
// tile in LDS next to lorder, then write it as 56 aligned float4s
// (block chunk = 896B = 14 full sectors, no cross-block sharing).
// Everything else byte-identical to R7.

typedef float nfloat4 __attribute__((ext_vector_type(4)));

constexpr int B  = 32;
constexpr int C  = 64;
constexpr int H  = 112;
constexpr int W  = 112;
constexpr int HO = 56;
constexpr int WO = 56;
constexpr int KK = 9;
constexpr int NPIX = HO * WO;          // 3136 windows per (b,c) plane
constexpr int BLK  = 256;
constexpr int LROW = 128;              // LDS row stride (floats)
constexpr int RPT  = 4;                // window-rows per block
constexpr int IR   = 2 * RPT + 1;      // input rows staged = 9

__global__ __launch_bounds__(BLK) void rrsvm_kernel(
    const float* __restrict__ x, const float* __restrict__ s,
    float* __restrict__ out, float* __restrict__ order)
{
    __shared__ float lx[IR * LROW];            // 4608 B
    __shared__ float lorder[RPT * WO * KK];    // 8064 B
    __shared__ float lout[RPT * WO];           // 896 B

    const int plane = blockIdx.y;              // b*C + c (block-uniform)
    const int ho0   = blockIdx.x;              // tile of 4 window-rows
    const int tid   = threadIdx.x;
    const int w     = tid >> 6;                // wave id 0..3 -> window-row
    const int lane  = tid & 63;                // lane -> window-col (56 live)
    const int c     = plane & (C - 1);

    const float* xp = x + (size_t)plane * (H * W);

    // ---- Stage 9 input rows (global rows 8*ho0-1 .. 8*ho0+7), shifted +1
    // in LDS so logical col -1 lands on the zeroed entry 0.
    if (tid < IR * (W / 4)) {                  // 252 float4 tasks
        const int r  = tid / (W / 4);          // 0..8
        const int cc = tid - r * (W / 4);      // 0..27
        const int grow = 8 * ho0 - 1 + r;      // -1..111
        nfloat4 val = (nfloat4)0.0f;
        if ((unsigned)grow < (unsigned)H)      // only ho0==0, r==0 is OOB
            val = *(const nfloat4*)(xp + grow * W + 4 * cc);
        float* dst = &lx[r * LROW + 1 + 4 * cc];
        dst[0] = val.x; dst[1] = val.y; dst[2] = val.z; dst[3] = val.w;
    }
    if (tid < IR) lx[tid * LROW] = 0.0f;       // logical col -1 = pad zero
    __syncthreads();

    // ---- Gather window from LDS.
    const bool live = (lane < WO);
    const int  lc   = live ? lane : 0;

    float v[KK];
    float fid[KK];
#pragma unroll
    for (int dy = 0; dy < 3; ++dy)
#pragma unroll
        for (int dx = 0; dx < 3; ++dx) {
            const int k = dy * 3 + dx;
            v[k]   = lx[(2 * w + dy) * LROW + 2 * lc + dx];
            fid[k] = (float)k;                 // compile-time constant
        }

    // ---- Sort descending by value; exact tie -> smaller index first.
    // (ids as floats: comparison exact for 0..8.)  Value path via
    // fmax/fmin (no NaNs in input); id path needs the full predicate.
    auto CE = [&](int a, int b) {
        const float va = v[a],   vb = v[b];
        const float fa = fid[a], fb = fid[b];
        const bool sw = (va < vb) || ((va == vb) && (fa > fb));
        v[a]   = fmaxf(va, vb);
        v[b]   = fminf(va, vb);
        fid[a] = sw ? fb : fa;
        fid[b] = sw ? fa : fb;
    };
    // Batcher odd-even mergesort on 0..7 (19 CEs) + insertion of 8 (8 CEs).
    CE(0,1); CE(2,3); CE(4,5); CE(6,7);
    CE(0,2); CE(1,3); CE(4,6); CE(5,7);
    CE(1,2); CE(5,6);
    CE(0,4); CE(1,5); CE(2,6); CE(3,7);
    CE(2,4); CE(3,5);
    CE(1,2); CE(3,4); CE(5,6);
    CE(7,8); CE(6,7); CE(5,6); CE(4,5); CE(3,4); CE(2,3); CE(1,2); CE(0,1);

    // ---- Weighted sum with per-channel rank weights (block-uniform c).
    const float* sc = s + c * KK;
    float acc = 0.0f;
#pragma unroll
    for (int k = 0; k < KK; ++k) acc = fmaf(v[k], sc[k], acc);

    if (live) {
        const int widx = w * WO + lane;        // window within tile, 0..223
        lout[widx] = acc;
#pragma unroll
        for (int k = 0; k < KK; ++k)
            lorder[widx * KK + k] = fid[k];    // stride 9 -> 2-way, free
    }
    __syncthreads();   // drains lgkm only: no vmem store issued yet

    // ---- All stores AFTER the last barrier, all sector-aligned.
    // order chunk: 8064 B = 126 sectors, aligned (plane*112896 + ho0*8064).
    nfloat4* __restrict__ ob =
        (nfloat4*)(order + ((size_t)plane * NPIX + (size_t)ho0 * RPT * WO) * KK);
    const nfloat4* __restrict__ lb = (const nfloat4*)lorder;
#pragma unroll
    for (int i = tid; i < RPT * WO * KK / 4; i += BLK)  // 504 float4
        __builtin_nontemporal_store(lb[i], ob + i);

    // out chunk: 896 B = 14 sectors, aligned (plane*12544 + ho0*896).
    if (tid < RPT * WO / 4) {                  // 56 float4
        nfloat4* __restrict__ outb =
            (nfloat4*)(out + (size_t)plane * NPIX + (size_t)ho0 * RPT * WO);
        __builtin_nontemporal_store(((const nfloat4*)lout)[tid], outb + tid);
    }
}

extern "C" void kernel_launch(void* const* d_in, const int* in_sizes, int n_in,
                              void* d_out, int out_size, void* d_ws, size_t ws_size,
                              hipStream_t stream) {
    const float* x = (const float*)d_in[0];
    const float* s = (const float*)d_in[1];
    float* out   = (float*)d_out;
    float* order = out + (size_t)B * C * NPIX;   // second output, flat after first

    dim3 grid(HO / RPT, B * C);                  // (14, 2048)
    rrsvm_kernel<<<grid, dim3(BLK), 0, stream>>>(x, s, out, order);
}